// Round 4
// baseline (492.258 us; speedup 1.0000x reference)
//
#include <hip/hip_runtime.h>
#include <hip/hip_bf16.h>

#define BB   8
#define TT   1024
#define NCBN 2
#define DD   128
#define KK   8192
#define MM   8192          // B*T queries per codebook

constexpr int OUT_IDX_OFF  = BB * 256 * TT;                // 2097152
constexpr int OUT_LOSS_OFF = OUT_IDX_OFF + BB * NCBN * TT; // 2113536

#define THR   0.45f        // >= 2*worst-case |y_bf16 - y_f32| (bound ~0.34)
#define QCAP  768

typedef __attribute__((ext_vector_type(8))) short   short8;   // 8 bf16
typedef __attribute__((ext_vector_type(4))) float   float4v;

__device__ __forceinline__ unsigned short f2bf(float v) {
    unsigned u = __float_as_uint(v);
    return (unsigned short)((u + 0x7FFFu + ((u >> 16) & 1u)) >> 16);  // RNE
}

// ---------------------------------------------------------------------------
// Pack x: transpose (B,256,T) -> xbf[n][m][d] bf16 + x2[n][m] fp32.
// Coalesced global reads (t-contiguous), LDS transpose, coalesced row writes.
// x2 = ascending-d fmaf chain of fp32 values (R1 association).
// grid (16, 16): bx=(b<<1)|n, by = 64-wide t-tile. 256 threads.
// ---------------------------------------------------------------------------
__global__ __launch_bounds__(256)
void pack_x_kernel(const float* __restrict__ x, unsigned short* __restrict__ xbf,
                   float* __restrict__ x2) {
    __shared__ float Ld[DD][65];
    const int b = blockIdx.x >> 1, n = blockIdx.x & 1;
    const int t0 = blockIdx.y * 64;
    const int tid = threadIdx.x;

    const float* base = x + ((size_t)(b * 256 + n * 128)) * TT + t0;
    const int dro = tid >> 2, q4 = tid & 3;
#pragma unroll
    for (int half = 0; half < 2; ++half) {
        int d = dro + half * 64;
        const float* rp = base + (size_t)d * TT + q4 * 16;
#pragma unroll
        for (int j = 0; j < 4; ++j) {
            float4 v = *(const float4*)(rp + j * 4);
            int t = q4 * 16 + j * 4;
            Ld[d][t + 0] = v.x; Ld[d][t + 1] = v.y;
            Ld[d][t + 2] = v.z; Ld[d][t + 3] = v.w;
        }
    }
    __syncthreads();

    if (tid < 64) {
        float s = 0.f;
        for (int d = 0; d < DD; ++d) { float v = Ld[d][tid]; s = fmaf(v, v, s); }
        x2[(size_t)n * MM + b * TT + t0 + tid] = s;
    }

    unsigned short* orow0 = xbf + ((size_t)n * MM + b * TT + t0) * DD;
#pragma unroll
    for (int pp = 0; pp < 4; ++pp) {
        int u = tid + pp * 256;            // 1024 units = 64 rows x 16 segs
        int tt = u >> 4, sg = u & 15;
        unsigned short tmp[8];
#pragma unroll
        for (int j = 0; j < 8; ++j) tmp[j] = f2bf(Ld[sg * 8 + j][tt]);
        uint4 pk;
        pk.x = (unsigned)tmp[0] | ((unsigned)tmp[1] << 16);
        pk.y = (unsigned)tmp[2] | ((unsigned)tmp[3] << 16);
        pk.z = (unsigned)tmp[4] | ((unsigned)tmp[5] << 16);
        pk.w = (unsigned)tmp[6] | ((unsigned)tmp[7] << 16);
        *(uint4*)(orow0 + (size_t)tt * DD + sg * 8) = pk;
    }
}

// ---------------------------------------------------------------------------
// Pack codebooks -> Cbf bf16 + c2 fp32 (ascending fmaf). Already coalesced.
// ---------------------------------------------------------------------------
__global__ __launch_bounds__(256)
void pack_c_kernel(const float* __restrict__ cb, unsigned short* __restrict__ cbf,
                   float* __restrict__ c2) {
    int g = blockIdx.x * 256 + threadIdx.x;   // n*K + k
    const float4* crow = (const float4*)(cb + (size_t)g * DD);
    unsigned short* orow = cbf + (size_t)g * DD;
    float s = 0.f;
#pragma unroll 4
    for (int i2 = 0; i2 < 16; ++i2) {
        float4 v0 = crow[2 * i2];
        float4 v1 = crow[2 * i2 + 1];
        s = fmaf(v0.x, v0.x, s); s = fmaf(v0.y, v0.y, s);
        s = fmaf(v0.z, v0.z, s); s = fmaf(v0.w, v0.w, s);
        s = fmaf(v1.x, v1.x, s); s = fmaf(v1.y, v1.y, s);
        s = fmaf(v1.z, v1.z, s); s = fmaf(v1.w, v1.w, s);
        uint4 pk;
        pk.x = (unsigned)f2bf(v0.x) | ((unsigned)f2bf(v0.y) << 16);
        pk.y = (unsigned)f2bf(v0.z) | ((unsigned)f2bf(v0.w) << 16);
        pk.z = (unsigned)f2bf(v1.x) | ((unsigned)f2bf(v1.y) << 16);
        pk.w = (unsigned)f2bf(v1.z) | ((unsigned)f2bf(v1.w) << 16);
        *(uint4*)(orow + i2 * 8) = pk;
    }
    c2[g] = s;
}

// ---------------------------------------------------------------------------
// Exact fp32 rescore: identical association to the R1 passing kernel.
// atomicMin on packed (s_bits<<32 | k) = "min s, then lowest k" (s > 0 here).
// ---------------------------------------------------------------------------
__device__ void rescore_one(int n, int m, int k,
                            const float* __restrict__ x, const float* __restrict__ cb,
                            const float* __restrict__ x2, const float* __restrict__ c2,
                            unsigned long long* __restrict__ pmin) {
    int b = m >> 10, t = m & (TT - 1);
    const float* xp = x + ((size_t)(b * 256 + n * 128)) * TT + t;
    const float* cp = cb + ((size_t)(n * KK + k)) * DD;
    float xc = 0.f;
    for (int d = 0; d < DD; ++d)
        xc = fmaf(xp[(size_t)d * TT], cp[d], xc);
    float u = x2[n * MM + m] - 2.0f * xc;
    float s = u + c2[n * KK + k];
    unsigned long long pk = ((unsigned long long)__float_as_uint(s) << 32) | (unsigned)k;
    atomicMin(pmin + (size_t)n * MM + m, pk);
}

// ---------------------------------------------------------------------------
// Screening. 1D grid of 512: combo = id&7 -> (n,ks); qt = id>>3.
// With round-robin XCD dispatch, each XCD hosts one combo -> its 512 KB code
// stream stays L2-resident across all 64 q-tile blocks (perf heuristic only).
// LDS XOR swizzle: phys 16B-seg = seg ^ (row&15); tile bases %16 == 0 so
// fragment reads/writes are conflict-minimal. Next chunk prefetched into
// registers during compute (latency hidden behind 32 MFMAs).
// ---------------------------------------------------------------------------
__global__ __launch_bounds__(512, 4)
void screen_kernel(const unsigned short* __restrict__ xbf,
                   const unsigned short* __restrict__ cbf,
                   const float* __restrict__ c2,
                   const float* __restrict__ x,
                   const float* __restrict__ cb32,
                   const float* __restrict__ x2,
                   unsigned long long* __restrict__ pmin) {
    __shared__ __align__(16) unsigned short Qsh[128 * 128];   // 32 KB
    __shared__ __align__(16) unsigned short Ash[128 * 128];   // 32 KB
    __shared__ unsigned int   minU[128];
    __shared__ float          c2s[128];
    __shared__ unsigned int   qcnt;
    __shared__ unsigned int   queue[QCAP];

    const int tid = threadIdx.x;
    const int id  = blockIdx.x;
    const int n   = id & 1;
    const int ks  = (id >> 1) & 3;
    const int qt  = id >> 3;           // 0..63
    const int m0  = qt * 128;
    const int k0  = ks * 2048;

    const int wave = tid >> 6, lane = tid & 63;
    const int cw = wave & 3, qw = wave >> 2;
    const int quad = lane >> 4, l15 = lane & 15;

    // staging map: unit i -> row=i>>4, logical seg=(i&15)^(row&15)
    int sunit[4], soff[4];
#pragma unroll
    for (int p = 0; p < 4; ++p) {
        int i = tid + p * 512;
        int row = i >> 4;
        int seg = (i & 15) ^ (row & 15);
        sunit[p] = i;
        soff[p]  = row * DD + seg * 8;
    }

    // ---- stage queries (once)
    {
        const unsigned short* src = xbf + ((size_t)n * MM + m0) * DD;
#pragma unroll
        for (int p = 0; p < 4; ++p) {
            uint4 v = *(const uint4*)(src + soff[p]);
            *(uint4*)(&Qsh[sunit[p] * 8]) = v;
        }
    }
    if (tid < 128) minU[tid] = 0xFFFFFFFFu;
    if (tid == 0)  qcnt = 0;
    __syncthreads();

    // ---- query B-fragments (whole D=128) register-resident
    short8 bfr[4][4];                      // [tq][k4]
#pragma unroll
    for (int tq = 0; tq < 4; ++tq) {
        int q = qw * 64 + tq * 16 + l15;   // q&15 == l15
#pragma unroll
        for (int k4 = 0; k4 < 4; ++k4) {
            int seg = k4 * 4 + quad;
            bfr[tq][k4] = *(const short8*)(&Qsh[q * 128 + ((seg ^ l15) * 8)]);
        }
    }

    float mloc[4] = {3.4e38f, 3.4e38f, 3.4e38f, 3.4e38f};
    float thr[4]  = {3.4e38f, 3.4e38f, 3.4e38f, 3.4e38f};

    const unsigned short* asrc0 = cbf + ((size_t)n * KK + k0) * DD;
    const float*          c2p   = c2 + (size_t)n * KK + k0;

    // initial prefetch (chunk 0)
    uint4  pf[4];
    float4 pfc2;
#pragma unroll
    for (int p = 0; p < 4; ++p) pf[p] = *(const uint4*)(asrc0 + soff[p]);
    if (tid < 32) pfc2 = *(const float4*)(c2p + tid * 4);

#pragma unroll
    for (int phase = 0; phase < 2; ++phase) {
        for (int ch = 0; ch < 16; ++ch) {
            __syncthreads();               // Ash free
#pragma unroll
            for (int p = 0; p < 4; ++p)
                *(uint4*)(&Ash[sunit[p] * 8]) = pf[p];
            if (tid < 32) *(float4*)&c2s[tid * 4] = pfc2;
            __syncthreads();               // Ash ready

            // prefetch next chunk (wraps to 0 for next phase)
            if (!(phase == 1 && ch == 15)) {
                int nch = (ch + 1) & 15;
                const unsigned short* sn = asrc0 + (size_t)nch * 128 * DD;
#pragma unroll
                for (int p = 0; p < 4; ++p) pf[p] = *(const uint4*)(sn + soff[p]);
                if (tid < 32) pfc2 = *(const float4*)(c2p + nch * 128 + tid * 4);
            }

            float4v acc[2][4];
#pragma unroll
            for (int tc = 0; tc < 2; ++tc)
#pragma unroll
                for (int tq = 0; tq < 4; ++tq)
                    acc[tc][tq] = (float4v){0.f, 0.f, 0.f, 0.f};

#pragma unroll
            for (int k4 = 0; k4 < 4; ++k4) {
#pragma unroll
                for (int tc = 0; tc < 2; ++tc) {
                    int r = cw * 32 + tc * 16 + l15;       // r&15 == l15
                    int seg = k4 * 4 + quad;
                    short8 a = *(const short8*)(&Ash[r * 128 + ((seg ^ l15) * 8)]);
#pragma unroll
                    for (int tq = 0; tq < 4; ++tq)
                        acc[tc][tq] = __builtin_amdgcn_mfma_f32_16x16x32_bf16(
                            a, bfr[tq][k4], acc[tc][tq], 0, 0, 0);
                }
            }

            // epilogue: y = c2 - 2*xc  (x2 query-constant, argmin-invariant)
#pragma unroll
            for (int tc = 0; tc < 2; ++tc) {
                float4v c2r = *(const float4v*)(&c2s[cw * 32 + tc * 16 + quad * 4]);
#pragma unroll
                for (int tq = 0; tq < 4; ++tq) {
#pragma unroll
                    for (int rg = 0; rg < 4; ++rg) {
                        float y = fmaf(-2.0f, acc[tc][tq][rg], c2r[rg]);
                        if (phase == 0) {
                            mloc[tq] = fminf(mloc[tq], y);
                        } else if (y <= thr[tq]) {
                            unsigned idx  = atomicAdd(&qcnt, 1u);
                            unsigned code = (unsigned)(ch * 128 + cw * 32 + tc * 16 + quad * 4 + rg);
                            unsigned q    = (unsigned)(qw * 64 + tq * 16 + l15);
                            if (idx < QCAP) queue[idx] = (q << 11) | code;
                            else rescore_one(n, m0 + (int)q, k0 + (int)code,
                                             x, cb32, x2, c2, pmin);
                        }
                    }
                }
            }
        }

        if (phase == 0) {
            // merge per-query mins: shuffle across quads, then LDS atomicMin
#pragma unroll
            for (int tq = 0; tq < 4; ++tq) {
                float v = mloc[tq];
                v = fminf(v, __shfl_xor(v, 16, 64));
                v = fminf(v, __shfl_xor(v, 32, 64));
                if (quad == 0) {
                    unsigned u  = __float_as_uint(v);
                    unsigned mu = (u & 0x80000000u) ? ~u : (u | 0x80000000u);
                    atomicMin(&minU[qw * 64 + tq * 16 + l15], mu);
                }
            }
            __syncthreads();
#pragma unroll
            for (int tq = 0; tq < 4; ++tq) {
                unsigned mu = minU[qw * 64 + tq * 16 + l15];
                unsigned u  = (mu & 0x80000000u) ? (mu & 0x7FFFFFFFu) : ~mu;
                thr[tq] = __uint_as_float(u) + THR;
            }
        }
    }

    __syncthreads();
    unsigned total = qcnt; if (total > QCAP) total = QCAP;
    for (unsigned i = tid; i < total; i += 512) {
        unsigned ent = queue[i];
        rescore_one(n, m0 + (int)(ent >> 11), k0 + (int)(ent & 2047u),
                    x, cb32, x2, c2, pmin);
    }
}

// ---------------------------------------------------------------------------
// Gather (transposed): stage selected code rows in LDS, write d-major
// coalesced, read x at same offsets for the loss.
// grid (16, 16): bx=(b<<1)|n, by = 64-wide t-tile. 256 threads.
// ---------------------------------------------------------------------------
__global__ __launch_bounds__(256)
void gather_kernel(const float* __restrict__ x, const float* __restrict__ cb,
                   const unsigned long long* __restrict__ pmin,
                   float* __restrict__ out) {
    __shared__ float Cr[64][DD + 1];   // 33 KB
    __shared__ int   kid[64];
    const int b = blockIdx.x >> 1, n = blockIdx.x & 1;
    const int t0 = blockIdx.y * 64;
    const int tid = threadIdx.x;

    if (tid < 64) {
        int t = t0 + tid;
        int k = (int)(pmin[(size_t)n * MM + b * TT + t] & 0xFFFFFFFFull);
        kid[tid] = k;
        out[OUT_IDX_OFF + (b * NCBN + n) * TT + t] = (float)k;
    }
    __syncthreads();

    {   // stage code rows: 4 lanes per row, coalesced 512 B per row
        int row = tid >> 2, q4 = tid & 3;
        const float* cp = cb + ((size_t)n * KK + kid[row]) * DD + q4 * 32;
#pragma unroll
        for (int j = 0; j < 8; ++j) {
            float4 v = *(const float4*)(cp + j * 4);
            int d = q4 * 32 + j * 4;
            Cr[row][d + 0] = v.x; Cr[row][d + 1] = v.y;
            Cr[row][d + 2] = v.z; Cr[row][d + 3] = v.w;
        }
    }
    __syncthreads();

    float lsum = 0.f;
    const float* xb = x  + ((size_t)(b * 256 + n * 128)) * TT + t0;
    float*       ob = out + ((size_t)(b * 256 + n * 128)) * TT + t0;
#pragma unroll
    for (int pp = 0; pp < 8; ++pp) {
        int u  = tid + pp * 256;       // 2048 units = 128 d x 16 float4
        int d  = u >> 4, ts = (u & 15) * 4;
        float4 xv = *(const float4*)(xb + (size_t)d * TT + ts);
        float4 qv = { Cr[ts + 0][d], Cr[ts + 1][d], Cr[ts + 2][d], Cr[ts + 3][d] };
        *(float4*)(ob + (size_t)d * TT + ts) = qv;
        float e;
        e = xv.x - qv.x; lsum = fmaf(e, e, lsum);
        e = xv.y - qv.y; lsum = fmaf(e, e, lsum);
        e = xv.z - qv.z; lsum = fmaf(e, e, lsum);
        e = xv.w - qv.w; lsum = fmaf(e, e, lsum);
    }

#pragma unroll
    for (int o = 32; o > 0; o >>= 1) lsum += __shfl_down(lsum, o, 64);
    __shared__ float wsum[4];
    int lane = tid & 63, w = tid >> 6;
    if (lane == 0) wsum[w] = lsum;
    __syncthreads();
    if (tid == 0) {
        float tot = wsum[0] + wsum[1] + wsum[2] + wsum[3];
        atomicAdd(out + OUT_LOSS_OFF, tot * 2.384185791015625e-7f);  // 2^-22
    }
}

// ---------------------------------------------------------------------------
extern "C" void kernel_launch(void* const* d_in, const int* in_sizes, int n_in,
                              void* d_out, int out_size, void* d_ws, size_t ws_size,
                              hipStream_t stream) {
    (void)in_sizes; (void)n_in; (void)out_size; (void)ws_size;
    const float* x  = (const float*)d_in[0];
    const float* cb = (const float*)d_in[1];
    float* out = (float*)d_out;

    char* ws = (char*)d_ws;
    unsigned short* xbf = (unsigned short*)(ws);                       // 4 MiB
    unsigned short* cbf = (unsigned short*)(ws + (4u << 20));          // 4 MiB
    float* x2 = (float*)(ws + (8u << 20));                             // 64 KiB
    float* c2 = (float*)(ws + (8u << 20) + (64u << 10));               // 64 KiB
    unsigned long long* pmin =
        (unsigned long long*)(ws + (8u << 20) + (128u << 10));         // 128 KiB

    pack_x_kernel<<<dim3(16, 16), 256, 0, stream>>>(x, xbf, x2);
    pack_c_kernel<<<dim3(64), 256, 0, stream>>>(cb, cbf, c2);
    hipMemsetAsync(pmin, 0xFF, (size_t)NCBN * MM * 8, stream);
    hipMemsetAsync((char*)d_out + (size_t)OUT_LOSS_OFF * 4, 0, 4, stream);

    screen_kernel<<<dim3(512), 512, 0, stream>>>(xbf, cbf, c2, x, cb, x2, pmin);
    gather_kernel<<<dim3(16, 16), 256, 0, stream>>>(x, cb, pmin, out);
}

// Round 5
// 184.836 us; speedup vs baseline: 2.6632x; 2.6632x over previous
//
#include <hip/hip_runtime.h>
#include <hip/hip_bf16.h>

#define BB   8
#define TT   1024
#define NCBN 2
#define DD   128
#define KK   8192
#define MM   8192          // B*T queries per codebook

constexpr int OUT_IDX_OFF  = BB * 256 * TT;                // 2097152
constexpr int OUT_LOSS_OFF = OUT_IDX_OFF + BB * NCBN * TT; // 2113536

#define THR   0.45f        // >= 2*worst-case |y_bf16 - y_f32| (bound ~0.34)
#define QCAP  768

typedef __attribute__((ext_vector_type(8))) short   short8;   // 8 bf16
typedef __attribute__((ext_vector_type(4))) float   float4v;

__device__ __forceinline__ unsigned short f2bf(float v) {
    unsigned u = __float_as_uint(v);
    return (unsigned short)((u + 0x7FFFu + ((u >> 16) & 1u)) >> 16);  // RNE
}

__device__ __forceinline__ void gl_lds16(const void* g, void* l) {
    __builtin_amdgcn_global_load_lds(
        (const __attribute__((address_space(1))) unsigned int*)g,
        (__attribute__((address_space(3))) unsigned int*)l, 16, 0, 0);
}

// ---------------------------------------------------------------------------
// Pack x: transpose (B,256,T) -> xbf[n][m][d] bf16 + x2[n][m] fp32 + pmin init.
// grid (16, 16): bx=(b<<1)|n, by = 64-wide t-tile. 256 threads.
// ---------------------------------------------------------------------------
__global__ __launch_bounds__(256)
void pack_x_kernel(const float* __restrict__ x, unsigned short* __restrict__ xbf,
                   float* __restrict__ x2, unsigned long long* __restrict__ pmin) {
    __shared__ float Ld[DD][65];
    const int b = blockIdx.x >> 1, n = blockIdx.x & 1;
    const int t0 = blockIdx.y * 64;
    const int tid = threadIdx.x;

    const float* base = x + ((size_t)(b * 256 + n * 128)) * TT + t0;
    const int dro = tid >> 2, q4 = tid & 3;
#pragma unroll
    for (int half = 0; half < 2; ++half) {
        int d = dro + half * 64;
        const float* rp = base + (size_t)d * TT + q4 * 16;
#pragma unroll
        for (int j = 0; j < 4; ++j) {
            float4 v = *(const float4*)(rp + j * 4);
            int t = q4 * 16 + j * 4;
            Ld[d][t + 0] = v.x; Ld[d][t + 1] = v.y;
            Ld[d][t + 2] = v.z; Ld[d][t + 3] = v.w;
        }
    }
    __syncthreads();

    if (tid < 64) {
        float s = 0.f;
        for (int d = 0; d < DD; ++d) { float v = Ld[d][tid]; s = fmaf(v, v, s); }
        x2[(size_t)n * MM + b * TT + t0 + tid] = s;
        pmin[(size_t)n * MM + b * TT + t0 + tid] = 0xFFFFFFFFFFFFFFFFull;
    }

    unsigned short* orow0 = xbf + ((size_t)n * MM + b * TT + t0) * DD;
#pragma unroll
    for (int pp = 0; pp < 4; ++pp) {
        int u = tid + pp * 256;            // 1024 units = 64 rows x 16 segs
        int tt = u >> 4, sg = u & 15;
        unsigned short tmp[8];
#pragma unroll
        for (int j = 0; j < 8; ++j) tmp[j] = f2bf(Ld[sg * 8 + j][tt]);
        uint4 pk;
        pk.x = (unsigned)tmp[0] | ((unsigned)tmp[1] << 16);
        pk.y = (unsigned)tmp[2] | ((unsigned)tmp[3] << 16);
        pk.z = (unsigned)tmp[4] | ((unsigned)tmp[5] << 16);
        pk.w = (unsigned)tmp[6] | ((unsigned)tmp[7] << 16);
        *(uint4*)(orow0 + (size_t)tt * DD + sg * 8) = pk;
    }
}

// ---------------------------------------------------------------------------
// Pack codebooks -> Cbf bf16 + c2 fp32 (ascending fmaf) + zero the loss slot.
// ---------------------------------------------------------------------------
__global__ __launch_bounds__(256)
void pack_c_kernel(const float* __restrict__ cb, unsigned short* __restrict__ cbf,
                   float* __restrict__ c2, float* __restrict__ out) {
    int g = blockIdx.x * 256 + threadIdx.x;   // n*K + k
    if (g == 0) out[OUT_LOSS_OFF] = 0.f;
    const float4* crow = (const float4*)(cb + (size_t)g * DD);
    unsigned short* orow = cbf + (size_t)g * DD;
    float s = 0.f;
#pragma unroll 4
    for (int i2 = 0; i2 < 16; ++i2) {
        float4 v0 = crow[2 * i2];
        float4 v1 = crow[2 * i2 + 1];
        s = fmaf(v0.x, v0.x, s); s = fmaf(v0.y, v0.y, s);
        s = fmaf(v0.z, v0.z, s); s = fmaf(v0.w, v0.w, s);
        s = fmaf(v1.x, v1.x, s); s = fmaf(v1.y, v1.y, s);
        s = fmaf(v1.z, v1.z, s); s = fmaf(v1.w, v1.w, s);
        uint4 pk;
        pk.x = (unsigned)f2bf(v0.x) | ((unsigned)f2bf(v0.y) << 16);
        pk.y = (unsigned)f2bf(v0.z) | ((unsigned)f2bf(v0.w) << 16);
        pk.z = (unsigned)f2bf(v1.x) | ((unsigned)f2bf(v1.y) << 16);
        pk.w = (unsigned)f2bf(v1.z) | ((unsigned)f2bf(v1.w) << 16);
        *(uint4*)(orow + i2 * 8) = pk;
    }
    c2[g] = s;
}

// ---------------------------------------------------------------------------
// Exact fp32 rescore: identical association to the R1 passing kernel.
// atomicMin on packed (s_bits<<32 | k) = "min s, then lowest k" (s > 0 here).
// ---------------------------------------------------------------------------
__device__ void rescore_one(int n, int m, int k,
                            const float* __restrict__ x, const float* __restrict__ cb,
                            const float* __restrict__ x2, const float* __restrict__ c2,
                            unsigned long long* __restrict__ pmin) {
    int b = m >> 10, t = m & (TT - 1);
    const float* xp = x + ((size_t)(b * 256 + n * 128)) * TT + t;
    const float* cp = cb + ((size_t)(n * KK + k)) * DD;
    float xc = 0.f;
    for (int d = 0; d < DD; ++d)
        xc = fmaf(xp[(size_t)d * TT], cp[d], xc);
    float u = x2[n * MM + m] - 2.0f * xc;
    float s = u + c2[n * KK + k];
    unsigned long long pk = ((unsigned long long)__float_as_uint(s) << 32) | (unsigned)k;
    atomicMin(pmin + (size_t)n * MM + m, pk);
}

// ---------------------------------------------------------------------------
// Screening v5. grid 512 x 256 threads (2 blocks/CU). combo = id&7 -> (n,ks)
// so each XCD keeps one 512 KB code stream L2-resident. 4 waves/block:
// qw = wave>>1 (2 x 64q), cw = wave&1 (2 x 64c). Per wave tile 64q x 64c:
// bfr (queries, full D) register-resident; A-frags from LDS (16 b128/chunk).
// Staging via async global_load_lds width=16 (no staging VGPRs, no spills).
// LDS XOR swizzle: phys 16B-seg = seg ^ (row&15); fragment reads conflict-free.
// ---------------------------------------------------------------------------
__global__ __launch_bounds__(256, 2)
void screen_kernel(const unsigned short* __restrict__ xbf,
                   const unsigned short* __restrict__ cbf,
                   const float* __restrict__ c2,
                   const float* __restrict__ x,
                   const float* __restrict__ cb32,
                   const float* __restrict__ x2,
                   unsigned long long* __restrict__ pmin) {
    __shared__ __align__(16) unsigned short Qsh[128 * 128];   // 32 KB
    __shared__ __align__(16) unsigned short Ash[128 * 128];   // 32 KB
    __shared__ unsigned int   minU[128];
    __shared__ float          c2s[128];
    __shared__ unsigned int   qcnt;
    __shared__ unsigned int   queue[QCAP];

    const int tid = threadIdx.x;
    const int id  = blockIdx.x;
    const int n   = id & 1;
    const int ks  = (id >> 1) & 3;
    const int qt  = id >> 3;           // 0..63
    const int m0  = qt * 128;
    const int k0  = ks * 2048;

    const int wave = tid >> 6, lane = tid & 63;
    const int cw = wave & 1, qw = wave >> 1;
    const int quad = lane >> 4, l15 = lane & 15;

    // per-lane staging offsets (bytes within one 32 KB tile), 8 issues/wave
    int goff[8];
#pragma unroll
    for (int p = 0; p < 8; ++p) {
        int u   = (p * 4 + wave) * 64 + lane;
        int row = u >> 4;
        int seg = (u & 15) ^ (row & 15);
        goff[p] = (row * DD + seg * 8) * 2;
    }

    // ---- stage queries (async -> Qsh)
    {
        const char* src = (const char*)(xbf + ((size_t)n * MM + m0) * DD);
#pragma unroll
        for (int p = 0; p < 8; ++p)
            gl_lds16(src + goff[p], &Qsh[(p * 4 + wave) * 512]);
    }
    if (tid < 128) minU[tid] = 0xFFFFFFFFu;
    if (tid == 0)  qcnt = 0;
    __syncthreads();

    // ---- query B-fragments (whole D=128) register-resident: 64 VGPRs
    short8 bfr[4][4];                      // [tq][k4]
#pragma unroll
    for (int tq = 0; tq < 4; ++tq) {
        int q = qw * 64 + tq * 16 + l15;   // q&15 == l15
#pragma unroll
        for (int k4 = 0; k4 < 4; ++k4) {
            int seg = k4 * 4 + quad;
            bfr[tq][k4] = *(const short8*)(&Qsh[q * 128 + ((seg ^ l15) * 8)]);
        }
    }

    float mloc[4] = {3.4e38f, 3.4e38f, 3.4e38f, 3.4e38f};
    float thr[4]  = {3.4e38f, 3.4e38f, 3.4e38f, 3.4e38f};

    const char*  asrc0 = (const char*)(cbf + ((size_t)n * KK + k0) * DD);
    const float* c2p   = c2 + (size_t)n * KK + k0;

#pragma unroll
    for (int phase = 0; phase < 2; ++phase) {
        for (int ch = 0; ch < 16; ++ch) {
            __syncthreads();               // Ash free
            {   // async stage code chunk -> Ash
                const char* src = asrc0 + (size_t)ch * (128 * DD * 2);
#pragma unroll
                for (int p = 0; p < 8; ++p)
                    gl_lds16(src + goff[p], &Ash[(p * 4 + wave) * 512]);
                if (tid < 32)
                    *(float4*)&c2s[tid * 4] =
                        *(const float4*)(c2p + ch * 128 + tid * 4);
            }
            __syncthreads();               // Ash ready (vmcnt drained)

            float4v acc[4][4];             // [tc][tq]: 64 VGPRs
#pragma unroll
            for (int tc = 0; tc < 4; ++tc)
#pragma unroll
                for (int tq = 0; tq < 4; ++tq)
                    acc[tc][tq] = (float4v){0.f, 0.f, 0.f, 0.f};

#pragma unroll
            for (int k4 = 0; k4 < 4; ++k4) {
                short8 a[4];
#pragma unroll
                for (int tc = 0; tc < 4; ++tc) {
                    int r = cw * 64 + tc * 16 + l15;       // r&15 == l15
                    int seg = k4 * 4 + quad;
                    a[tc] = *(const short8*)(&Ash[r * 128 + ((seg ^ l15) * 8)]);
                }
#pragma unroll
                for (int tc = 0; tc < 4; ++tc)
#pragma unroll
                    for (int tq = 0; tq < 4; ++tq)
                        acc[tc][tq] = __builtin_amdgcn_mfma_f32_16x16x32_bf16(
                            a[tc], bfr[tq][k4], acc[tc][tq], 0, 0, 0);
            }

            // epilogue: y = c2 - 2*xc  (x2 query-constant, argmin-invariant)
#pragma unroll
            for (int tc = 0; tc < 4; ++tc) {
                float4v c2r = *(const float4v*)(&c2s[cw * 64 + tc * 16 + quad * 4]);
#pragma unroll
                for (int tq = 0; tq < 4; ++tq) {
                    float y0 = fmaf(-2.0f, acc[tc][tq][0], c2r[0]);
                    float y1 = fmaf(-2.0f, acc[tc][tq][1], c2r[1]);
                    float y2 = fmaf(-2.0f, acc[tc][tq][2], c2r[2]);
                    float y3 = fmaf(-2.0f, acc[tc][tq][3], c2r[3]);
                    float m4 = fminf(fminf(y0, y1), fminf(y2, y3));
                    if (phase == 0) {
                        mloc[tq] = fminf(mloc[tq], m4);
                    } else if (m4 <= thr[tq]) {
                        float yv[4] = {y0, y1, y2, y3};
#pragma unroll
                        for (int rg = 0; rg < 4; ++rg) {
                            if (yv[rg] <= thr[tq]) {
                                unsigned idx  = atomicAdd(&qcnt, 1u);
                                unsigned code = (unsigned)(ch * 128 + cw * 64 + tc * 16 + quad * 4 + rg);
                                unsigned q    = (unsigned)(qw * 64 + tq * 16 + l15);
                                if (idx < QCAP) queue[idx] = (q << 11) | code;
                                else rescore_one(n, m0 + (int)q, k0 + (int)code,
                                                 x, cb32, x2, c2, pmin);
                            }
                        }
                    }
                }
            }
        }

        if (phase == 0) {
            // merge per-query mins: shuffle across quads, then LDS atomicMin
#pragma unroll
            for (int tq = 0; tq < 4; ++tq) {
                float v = mloc[tq];
                v = fminf(v, __shfl_xor(v, 16, 64));
                v = fminf(v, __shfl_xor(v, 32, 64));
                if (quad == 0) {
                    unsigned u  = __float_as_uint(v);
                    unsigned mu = (u & 0x80000000u) ? ~u : (u | 0x80000000u);
                    atomicMin(&minU[qw * 64 + tq * 16 + l15], mu);
                }
            }
            __syncthreads();
#pragma unroll
            for (int tq = 0; tq < 4; ++tq) {
                unsigned mu = minU[qw * 64 + tq * 16 + l15];
                unsigned u  = (mu & 0x80000000u) ? (mu & 0x7FFFFFFFu) : ~mu;
                thr[tq] = __uint_as_float(u) + THR;
            }
        }
    }

    __syncthreads();
    unsigned total = qcnt; if (total > QCAP) total = QCAP;
    for (unsigned i = tid; i < total; i += 256) {
        unsigned ent = queue[i];
        rescore_one(n, m0 + (int)(ent >> 11), k0 + (int)(ent & 2047u),
                    x, cb32, x2, c2, pmin);
    }
}

// ---------------------------------------------------------------------------
// Gather (transposed): stage selected code rows in LDS, write d-major
// coalesced, read x at same offsets for the loss.
// grid (16, 16): bx=(b<<1)|n, by = 64-wide t-tile. 256 threads.
// ---------------------------------------------------------------------------
__global__ __launch_bounds__(256)
void gather_kernel(const float* __restrict__ x, const float* __restrict__ cb,
                   const unsigned long long* __restrict__ pmin,
                   float* __restrict__ out) {
    __shared__ float Cr[64][DD + 1];   // 33 KB
    __shared__ int   kid[64];
    const int b = blockIdx.x >> 1, n = blockIdx.x & 1;
    const int t0 = blockIdx.y * 64;
    const int tid = threadIdx.x;

    if (tid < 64) {
        int t = t0 + tid;
        int k = (int)(pmin[(size_t)n * MM + b * TT + t] & 0xFFFFFFFFull);
        kid[tid] = k;
        out[OUT_IDX_OFF + (b * NCBN + n) * TT + t] = (float)k;
    }
    __syncthreads();

    {   // stage code rows: 4 lanes per row, coalesced 512 B per row
        int row = tid >> 2, q4 = tid & 3;
        const float* cp = cb + ((size_t)n * KK + kid[row]) * DD + q4 * 32;
#pragma unroll
        for (int j = 0; j < 8; ++j) {
            float4 v = *(const float4*)(cp + j * 4);
            int d = q4 * 32 + j * 4;
            Cr[row][d + 0] = v.x; Cr[row][d + 1] = v.y;
            Cr[row][d + 2] = v.z; Cr[row][d + 3] = v.w;
        }
    }
    __syncthreads();

    float lsum = 0.f;
    const float* xb = x  + ((size_t)(b * 256 + n * 128)) * TT + t0;
    float*       ob = out + ((size_t)(b * 256 + n * 128)) * TT + t0;
#pragma unroll
    for (int pp = 0; pp < 8; ++pp) {
        int u  = tid + pp * 256;       // 2048 units = 128 d x 16 float4
        int d  = u >> 4, ts = (u & 15) * 4;
        float4 xv = *(const float4*)(xb + (size_t)d * TT + ts);
        float4 qv = { Cr[ts + 0][d], Cr[ts + 1][d], Cr[ts + 2][d], Cr[ts + 3][d] };
        *(float4*)(ob + (size_t)d * TT + ts) = qv;
        float e;
        e = xv.x - qv.x; lsum = fmaf(e, e, lsum);
        e = xv.y - qv.y; lsum = fmaf(e, e, lsum);
        e = xv.z - qv.z; lsum = fmaf(e, e, lsum);
        e = xv.w - qv.w; lsum = fmaf(e, e, lsum);
    }

#pragma unroll
    for (int o = 32; o > 0; o >>= 1) lsum += __shfl_down(lsum, o, 64);
    __shared__ float wsum[4];
    int lane = tid & 63, w = tid >> 6;
    if (lane == 0) wsum[w] = lsum;
    __syncthreads();
    if (tid == 0) {
        float tot = wsum[0] + wsum[1] + wsum[2] + wsum[3];
        atomicAdd(out + OUT_LOSS_OFF, tot * 2.384185791015625e-7f);  // 2^-22
    }
}

// ---------------------------------------------------------------------------
extern "C" void kernel_launch(void* const* d_in, const int* in_sizes, int n_in,
                              void* d_out, int out_size, void* d_ws, size_t ws_size,
                              hipStream_t stream) {
    (void)in_sizes; (void)n_in; (void)out_size; (void)ws_size;
    const float* x  = (const float*)d_in[0];
    const float* cb = (const float*)d_in[1];
    float* out = (float*)d_out;

    char* ws = (char*)d_ws;
    unsigned short* xbf = (unsigned short*)(ws);                       // 4 MiB
    unsigned short* cbf = (unsigned short*)(ws + (4u << 20));          // 4 MiB
    float* x2 = (float*)(ws + (8u << 20));                             // 64 KiB
    float* c2 = (float*)(ws + (8u << 20) + (64u << 10));               // 64 KiB
    unsigned long long* pmin =
        (unsigned long long*)(ws + (8u << 20) + (128u << 10));         // 128 KiB

    pack_x_kernel<<<dim3(16, 16), 256, 0, stream>>>(x, xbf, x2, pmin);
    pack_c_kernel<<<dim3(64), 256, 0, stream>>>(cb, cbf, c2, out);

    screen_kernel<<<dim3(512), 256, 0, stream>>>(xbf, cbf, c2, x, cb, x2, pmin);
    gather_kernel<<<dim3(16, 16), 256, 0, stream>>>(x, cb, pmin, out);
}